// Round 1
// baseline (354.732 us; speedup 1.0000x reference)
//
#include <hip/hip_runtime.h>

#define T_TOK 1024
#define D_DIM 2048
#define E_NUM 32
#define F_DIM 768
#define K_TOP 8

typedef __bf16 v8bf __attribute__((ext_vector_type(8)));
typedef float v4f __attribute__((ext_vector_type(4)));
typedef unsigned short v8us __attribute__((ext_vector_type(8)));
typedef unsigned int v4u __attribute__((ext_vector_type(4)));

__device__ __forceinline__ unsigned short f2b(float f) {
  unsigned int u = __builtin_bit_cast(unsigned int, f);
  u += 0x7fffu + ((u >> 16) & 1u);   // RNE
  return (unsigned short)(u >> 16);
}
__device__ __forceinline__ float b2f(unsigned short s) {
  return __builtin_bit_cast(float, (unsigned int)s << 16);
}

// ---------------- Router: logits (fp32), top-8, bucket, x->bf16 ----------------
__global__ __launch_bounds__(256) void router_kernel(
    const float* __restrict__ x, const float* __restrict__ gw,
    unsigned short* __restrict__ xb, int* __restrict__ counts,
    int* __restrict__ tlist, int* __restrict__ topk_e, int* __restrict__ topk_p,
    float* __restrict__ topk_w, float* __restrict__ wlist)
{
  const int t = blockIdx.x, tid = threadIdx.x;
  const float* xr = x + (size_t)t * D_DIM;

  {  // convert this token's row to bf16
    v4f f0 = *reinterpret_cast<const v4f*>(xr + tid * 8);
    v4f f1 = *reinterpret_cast<const v4f*>(xr + tid * 8 + 4);
    v8us u;
    u[0] = f2b(f0[0]); u[1] = f2b(f0[1]); u[2] = f2b(f0[2]); u[3] = f2b(f0[3]);
    u[4] = f2b(f1[0]); u[5] = f2b(f1[1]); u[6] = f2b(f1[2]); u[7] = f2b(f1[3]);
    *reinterpret_cast<v8us*>(xb + (size_t)t * D_DIM + tid * 8) = u;
  }

  __shared__ float logits[E_NUM];
  const int lane = tid & 63, wave = tid >> 6;
  for (int j = 0; j < 8; ++j) {
    int e = wave * 8 + j;
    const float* wr = gw + (size_t)e * D_DIM;
    float s = 0.f;
#pragma unroll
    for (int i = 0; i < D_DIM / 64; ++i) s = fmaf(xr[lane + i * 64], wr[lane + i * 64], s);
#pragma unroll
    for (int off = 32; off > 0; off >>= 1) s += __shfl_xor(s, off);
    if (lane == 0) logits[e] = s;
  }
  __syncthreads();

  if (tid == 0) {
    float lg[E_NUM];
#pragma unroll
    for (int e2 = 0; e2 < E_NUM; ++e2) lg[e2] = logits[e2];
    int sel[K_TOP]; float sv[K_TOP];
    for (int k = 0; k < K_TOP; ++k) {
      int best = 0; float bv = -3.4e38f;
      for (int e2 = 0; e2 < E_NUM; ++e2)
        if (lg[e2] > bv) { bv = lg[e2]; best = e2; }
      sel[k] = best; sv[k] = bv; lg[best] = -3.4e38f;
    }
    // softmax over selected (== full softmax followed by top-k renorm)
    float mx = sv[0], s8 = 0.f, ww[K_TOP];
    for (int k = 0; k < K_TOP; ++k) { ww[k] = __expf(sv[k] - mx); s8 += ww[k]; }
    float inv = 1.f / s8;
    for (int k = 0; k < K_TOP; ++k) {
      float w = ww[k] * inv;
      int e2 = sel[k];
      int pos = atomicAdd(&counts[e2], 1);
      tlist[e2 * T_TOK + pos] = t;
      wlist[e2 * T_TOK + pos] = w;
      topk_e[t * K_TOP + k] = e2;
      topk_p[t * K_TOP + k] = pos;
      topk_w[t * K_TOP + k] = w;
    }
  }
}

__global__ void scan_kernel(const int* __restrict__ counts, int* __restrict__ offsets)
{
  if (threadIdx.x == 0) {
    int run = 0;
    for (int e = 0; e < E_NUM; ++e) { offsets[e] = run; run += counts[e]; }
  }
}

// ---------------- Gate+Up grouped GEMM, fused SiLU, h (bf16) ----------------
// block: 512 thr (8 waves, 4x2). tile: 256 tokens x 64 F-cols, BK=64, K=2048.
__global__ __launch_bounds__(512, 1) void gateup_kernel(
    const unsigned short* __restrict__ xb, const float* __restrict__ wg,
    const float* __restrict__ wu, const int* __restrict__ counts,
    const int* __restrict__ offsets, const int* __restrict__ tlist,
    unsigned short* __restrict__ hbuf)
{
  const int e = blockIdx.y;
  const int cnt = counts[e];
  const int tf = blockIdx.x % (F_DIM / 64);
  const int tm = blockIdx.x / (F_DIM / 64);
  if (tm * 256 >= cnt) return;

  __shared__ __align__(16) unsigned short As[256 * 64];   // 32 KB
  __shared__ __align__(16) unsigned short Bs[2][64 * 64]; // 2 x 8 KB

  const int tid = threadIdx.x;
  const int lane = tid & 63;
  const int wave = tid >> 6;
  const int wm = wave >> 1;  // 0..3
  const int wn = wave & 1;   // 0..1
  const int l15 = lane & 15;
  const int l4 = lane >> 4;

  // A staging plan: 4 x 16B granules per thread (256 rows x 8 granules)
  const unsigned short* asrc[4];
  int adst[4];
  bool aval[4];
#pragma unroll
  for (int i = 0; i < 4; ++i) {
    int gi = tid + i * 512;
    int row = gi >> 3, g = gi & 7;
    int rg = tm * 256 + row;
    bool v = (rg < cnt);
    int tok = v ? tlist[e * T_TOK + rg] : 0;
    aval[i] = v;
    asrc[i] = xb + (size_t)tok * D_DIM + g * 8;
    adst[i] = row * 64 + ((g ^ (row & 7)) * 8);
  }
  // B staging: one granule per thread for each of wg, wu (64 rows x 8 granules)
  const int brow = tid >> 3, bgr = tid & 7;
  const size_t bbase = ((size_t)e * F_DIM + (size_t)tf * 64 + brow) * D_DIM + bgr * 8;
  const float* bsrc0 = wg + bbase;
  const float* bsrc1 = wu + bbase;
  const int bdst = brow * 64 + ((bgr ^ (brow & 7)) * 8);

  v4f zero = {0.f, 0.f, 0.f, 0.f};
  v4f accg[4][2], accu[4][2];
#pragma unroll
  for (int fm = 0; fm < 4; ++fm)
#pragma unroll
    for (int fn = 0; fn < 2; ++fn) { accg[fm][fn] = zero; accu[fm][fn] = zero; }

  for (int k0 = 0; k0 < D_DIM; k0 += 64) {
#pragma unroll
    for (int i = 0; i < 4; ++i) {
      v4u v = {0u, 0u, 0u, 0u};
      if (aval[i]) v = *reinterpret_cast<const v4u*>(asrc[i] + k0);
      *reinterpret_cast<v4u*>(&As[adst[i]]) = v;
    }
#pragma unroll
    for (int b = 0; b < 2; ++b) {
      const float* p = (b == 0 ? bsrc0 : bsrc1) + k0;
      v4f f0 = *reinterpret_cast<const v4f*>(p);
      v4f f1 = *reinterpret_cast<const v4f*>(p + 4);
      v8us u;
      u[0] = f2b(f0[0]); u[1] = f2b(f0[1]); u[2] = f2b(f0[2]); u[3] = f2b(f0[3]);
      u[4] = f2b(f1[0]); u[5] = f2b(f1[1]); u[6] = f2b(f1[2]); u[7] = f2b(f1[3]);
      *reinterpret_cast<v8us*>(&Bs[b][bdst]) = u;
    }
    __syncthreads();

#pragma unroll
    for (int ks = 0; ks < 2; ++ks) {
      v8bf af[4], bg_[2], bu_[2];
#pragma unroll
      for (int fm = 0; fm < 4; ++fm) {
        int row = wm * 64 + fm * 16 + l15;
        int gg = ks * 4 + l4;
        af[fm] = __builtin_bit_cast(v8bf,
            *reinterpret_cast<const v8us*>(&As[row * 64 + ((gg ^ (row & 7)) * 8)]));
      }
#pragma unroll
      for (int fn = 0; fn < 2; ++fn) {
        int row = wn * 32 + fn * 16 + l15;
        int gg = ks * 4 + l4;
        int ad = row * 64 + ((gg ^ (row & 7)) * 8);
        bg_[fn] = __builtin_bit_cast(v8bf, *reinterpret_cast<const v8us*>(&Bs[0][ad]));
        bu_[fn] = __builtin_bit_cast(v8bf, *reinterpret_cast<const v8us*>(&Bs[1][ad]));
      }
#pragma unroll
      for (int fm = 0; fm < 4; ++fm)
#pragma unroll
        for (int fn = 0; fn < 2; ++fn) {
          accg[fm][fn] = __builtin_amdgcn_mfma_f32_16x16x32_bf16(af[fm], bg_[fn], accg[fm][fn], 0, 0, 0);
          accu[fm][fn] = __builtin_amdgcn_mfma_f32_16x16x32_bf16(af[fm], bu_[fn], accu[fm][fn], 0, 0, 0);
        }
    }
    __syncthreads();
  }

  const int off_e = offsets[e];
#pragma unroll
  for (int fm = 0; fm < 4; ++fm)
#pragma unroll
    for (int fn = 0; fn < 2; ++fn)
#pragma unroll
      for (int i = 0; i < 4; ++i) {
        int rloc = wm * 64 + fm * 16 + l4 * 4 + i;
        int rg = tm * 256 + rloc;
        if (rg < cnt) {
          int col = tf * 64 + wn * 32 + fn * 16 + l15;
          float g = accg[fm][fn][i];
          float uu = accu[fm][fn][i];
          float h = g * (1.f / (1.f + __expf(-g))) * uu;
          hbuf[(size_t)(off_e + rg) * F_DIM + col] = f2b(h);
        }
      }
}

// ---------------- Down grouped GEMM: y = h @ wd[e]^T ----------------
// tile: 256 rows x 64 D-cols, BK=64, K=768.
template <int STAGE>
__global__ __launch_bounds__(512, 1) void down_kernel(
    const unsigned short* __restrict__ hbuf, const float* __restrict__ wd,
    const int* __restrict__ counts, const int* __restrict__ offsets,
    const int* __restrict__ tlist, const float* __restrict__ wlist,
    unsigned short* __restrict__ ybuf, float* __restrict__ out)
{
  const int e = blockIdx.y;
  const int cnt = counts[e];
  const int td = blockIdx.x % (D_DIM / 64);
  const int tm = blockIdx.x / (D_DIM / 64);
  if (tm * 256 >= cnt) return;
  const int off_e = offsets[e];

  __shared__ __align__(16) unsigned short As[256 * 64];
  __shared__ __align__(16) unsigned short Bs[64 * 64];

  const int tid = threadIdx.x;
  const int lane = tid & 63;
  const int wave = tid >> 6;
  const int wm = wave >> 1;
  const int wn = wave & 1;
  const int l15 = lane & 15;
  const int l4 = lane >> 4;

  const unsigned short* asrc[4];
  int adst[4];
  bool aval[4];
#pragma unroll
  for (int i = 0; i < 4; ++i) {
    int gi = tid + i * 512;
    int row = gi >> 3, g = gi & 7;
    int rg = tm * 256 + row;
    bool v = (rg < cnt);
    aval[i] = v;
    asrc[i] = hbuf + (size_t)(off_e + (v ? rg : 0)) * F_DIM + g * 8;
    adst[i] = row * 64 + ((g ^ (row & 7)) * 8);
  }
  const int brow = tid >> 3, bgr = tid & 7;
  const float* bsrc = wd + ((size_t)e * D_DIM + (size_t)td * 64 + brow) * F_DIM + bgr * 8;
  const int bdst = brow * 64 + ((bgr ^ (brow & 7)) * 8);

  v4f zero = {0.f, 0.f, 0.f, 0.f};
  v4f acc[4][2];
#pragma unroll
  for (int fm = 0; fm < 4; ++fm)
#pragma unroll
    for (int fn = 0; fn < 2; ++fn) acc[fm][fn] = zero;

  for (int k0 = 0; k0 < F_DIM; k0 += 64) {
#pragma unroll
    for (int i = 0; i < 4; ++i) {
      v4u v = {0u, 0u, 0u, 0u};
      if (aval[i]) v = *reinterpret_cast<const v4u*>(asrc[i] + k0);
      *reinterpret_cast<v4u*>(&As[adst[i]]) = v;
    }
    {
      const float* p = bsrc + k0;
      v4f f0 = *reinterpret_cast<const v4f*>(p);
      v4f f1 = *reinterpret_cast<const v4f*>(p + 4);
      v8us u;
      u[0] = f2b(f0[0]); u[1] = f2b(f0[1]); u[2] = f2b(f0[2]); u[3] = f2b(f0[3]);
      u[4] = f2b(f1[0]); u[5] = f2b(f1[1]); u[6] = f2b(f1[2]); u[7] = f2b(f1[3]);
      *reinterpret_cast<v8us*>(&Bs[bdst]) = u;
    }
    __syncthreads();

#pragma unroll
    for (int ks = 0; ks < 2; ++ks) {
      v8bf af[4], bf_[2];
#pragma unroll
      for (int fm = 0; fm < 4; ++fm) {
        int row = wm * 64 + fm * 16 + l15;
        int gg = ks * 4 + l4;
        af[fm] = __builtin_bit_cast(v8bf,
            *reinterpret_cast<const v8us*>(&As[row * 64 + ((gg ^ (row & 7)) * 8)]));
      }
#pragma unroll
      for (int fn = 0; fn < 2; ++fn) {
        int row = wn * 32 + fn * 16 + l15;
        int gg = ks * 4 + l4;
        bf_[fn] = __builtin_bit_cast(v8bf,
            *reinterpret_cast<const v8us*>(&Bs[row * 64 + ((gg ^ (row & 7)) * 8)]));
      }
#pragma unroll
      for (int fm = 0; fm < 4; ++fm)
#pragma unroll
        for (int fn = 0; fn < 2; ++fn)
          acc[fm][fn] = __builtin_amdgcn_mfma_f32_16x16x32_bf16(af[fm], bf_[fn], acc[fm][fn], 0, 0, 0);
    }
    __syncthreads();
  }

#pragma unroll
  for (int fm = 0; fm < 4; ++fm)
#pragma unroll
    for (int fn = 0; fn < 2; ++fn)
#pragma unroll
      for (int i = 0; i < 4; ++i) {
        int rloc = wm * 64 + fm * 16 + l4 * 4 + i;
        int rg = tm * 256 + rloc;
        if (rg < cnt) {
          int col = td * 64 + wn * 32 + fn * 16 + l15;
          float y = acc[fm][fn][i];
          if (STAGE) {
            ybuf[(size_t)(off_e + rg) * D_DIM + col] = f2b(y);
          } else {
            int tok = tlist[e * T_TOK + rg];
            float w = wlist[e * T_TOK + rg];
            atomicAdd(out + (size_t)tok * D_DIM + col, w * y);
          }
        }
      }
}

// ---------------- Combine: out[t] = sum_k w_k * y[slot_k] ----------------
__global__ __launch_bounds__(256) void combine_kernel(
    const unsigned short* __restrict__ ybuf, const int* __restrict__ topk_e,
    const int* __restrict__ topk_p, const float* __restrict__ topk_w,
    const int* __restrict__ offsets, float* __restrict__ out)
{
  const int t = blockIdx.x, tid = threadIdx.x;
  const int d0 = tid * 8;
  float acc[8] = {0.f, 0.f, 0.f, 0.f, 0.f, 0.f, 0.f, 0.f};
#pragma unroll
  for (int k = 0; k < K_TOP; ++k) {
    int e = topk_e[t * K_TOP + k];
    int slot = offsets[e] + topk_p[t * K_TOP + k];
    float w = topk_w[t * K_TOP + k];
    v8us v = *reinterpret_cast<const v8us*>(ybuf + (size_t)slot * D_DIM + d0);
#pragma unroll
    for (int j = 0; j < 8; ++j) acc[j] += w * b2f(v[j]);
  }
  v4f o0 = {acc[0], acc[1], acc[2], acc[3]};
  v4f o1 = {acc[4], acc[5], acc[6], acc[7]};
  *reinterpret_cast<v4f*>(out + (size_t)t * D_DIM + d0) = o0;
  *reinterpret_cast<v4f*>(out + (size_t)t * D_DIM + d0 + 4) = o1;
}

extern "C" void kernel_launch(void* const* d_in, const int* in_sizes, int n_in,
                              void* d_out, int out_size, void* d_ws, size_t ws_size,
                              hipStream_t stream)
{
  const float* x  = (const float*)d_in[0];
  const float* gw = (const float*)d_in[1];
  const float* wg = (const float*)d_in[2];
  const float* wu = (const float*)d_in[3];
  const float* wd = (const float*)d_in[4];
  float* out = (float*)d_out;

  char* p = (char*)d_ws;
  auto alloc = [&](size_t bytes) {
    char* r = p;
    p += (bytes + 255) & ~(size_t)255;
    return r;
  };
  int* counts   = (int*)alloc(E_NUM * 4);
  int* offsets  = (int*)alloc(E_NUM * 4);
  int* tlist    = (int*)alloc((size_t)E_NUM * T_TOK * 4);
  float* wlist  = (float*)alloc((size_t)E_NUM * T_TOK * 4);
  int* topk_e   = (int*)alloc((size_t)T_TOK * K_TOP * 4);
  int* topk_p   = (int*)alloc((size_t)T_TOK * K_TOP * 4);
  float* topk_w = (float*)alloc((size_t)T_TOK * K_TOP * 4);
  unsigned short* xb   = (unsigned short*)alloc((size_t)T_TOK * D_DIM * 2);
  unsigned short* hbuf = (unsigned short*)alloc((size_t)T_TOK * K_TOP * F_DIM * 2);
  size_t need_atomic = (size_t)(p - (char*)d_ws);
  unsigned short* ybuf = (unsigned short*)alloc((size_t)T_TOK * K_TOP * D_DIM * 2);
  size_t need_stage = (size_t)(p - (char*)d_ws);

  if (ws_size < need_atomic) return;  // cannot run safely
  const bool stage = (ws_size >= need_stage);

  hipMemsetAsync(counts, 0, E_NUM * 4, stream);
  router_kernel<<<T_TOK, 256, 0, stream>>>(x, gw, xb, counts, tlist, topk_e, topk_p, topk_w, wlist);
  scan_kernel<<<1, 64, 0, stream>>>(counts, offsets);
  gateup_kernel<<<dim3((F_DIM / 64) * 4, E_NUM), 512, 0, stream>>>(
      xb, wg, wu, counts, offsets, tlist, hbuf);
  if (stage) {
    down_kernel<1><<<dim3((D_DIM / 64) * 4, E_NUM), 512, 0, stream>>>(
        hbuf, wd, counts, offsets, tlist, wlist, ybuf, out);
    combine_kernel<<<T_TOK, 256, 0, stream>>>(ybuf, topk_e, topk_p, topk_w, offsets, out);
  } else {
    hipMemsetAsync(out, 0, (size_t)out_size * 4, stream);
    down_kernel<0><<<dim3((D_DIM / 64) * 4, E_NUM), 512, 0, stream>>>(
        hbuf, wd, counts, offsets, tlist, wlist, ybuf, out);
  }
}